// Round 4
// baseline (942.695 us; speedup 1.0000x reference)
//
#include <hip/hip_runtime.h>
#include <math.h>

// Problem constants
#define BB 16
#define NN 4096
#define DD 256
#define CC 8
#define KK 512
#define SD 32
#define NTOK (BB * NN)            // 65536
#define IDS_N (NTOK * CC)         // 524288
#define QN (NTOK * DD)            // 16777216
#define OFF_Q   (IDS_N)
#define OFF_ST  (IDS_N + QN)
#define OFF_SC  (IDS_N + 2 * QN)

// Margin gate: MFMA bf16-triple score error <= ~6e-6 worst; np-vs-exact flip
// window ~1.6e-5. GUARD 1e-4 >= 3x stacked worst case; flags ~1.5%.
#define GUARD 1e-4f
#define CAP 65536

// ws layout
#define WSO_MSE   0
#define WSO_MASK  8
#define WSO_CNT   16
#define WSO_HIST  1024
#define WSO_CSQ   (WSO_HIST + 16384)
#define WSO_LIST  (WSO_CSQ + 16384)
#define WSO_CBH   (WSO_LIST + 262144)
#define WSO_CBL   (WSO_CBH + 262144)
#define WS_ZERO   (WSO_HIST + 16384)    // zero mse, mask_sum, count, hist

typedef float f32x4 __attribute__((ext_vector_type(4)));
typedef short bf16x8 __attribute__((ext_vector_type(8)));

__device__ inline unsigned short f2bf_rne(float f) {
    unsigned u = __float_as_uint(f);
    u += 0x7fff + ((u >> 16) & 1);
    return (unsigned short)(u >> 16);
}
__device__ inline float bf2f(unsigned short h) {
    return __uint_as_float(((unsigned)h) << 16);
}

// ---------------------------------------------------------------------------
// Prep: csq (f64, same fma order as the verified round-2 kernel), bf16 hi/lo
// split of the codebook, and parallel mask-sum.
__global__ __launch_bounds__(256) void vq_prep(
    const float* __restrict__ cbs, const float* __restrict__ mask,
    float* __restrict__ csqf, unsigned short* __restrict__ cbh,
    unsigned short* __restrict__ cbl, double* __restrict__ mask_sum)
{
    __shared__ double red[256];
    const int tid = threadIdx.x;
    const int cell = blockIdx.x * 256 + tid;     // 16 blocks -> 4096 cells
    const float* cp = cbs + (size_t)cell * SD;
    unsigned short* hp = cbh + (size_t)cell * SD;
    unsigned short* lp = cbl + (size_t)cell * SD;
    double s = 0.0;
    #pragma unroll
    for (int j = 0; j < 8; ++j) {
        float4 v = ((const float4*)cp)[j];
        float vv[4] = {v.x, v.y, v.z, v.w};
        #pragma unroll
        for (int q = 0; q < 4; ++q) {
            double dv = (double)vv[q];
            s = fma(dv, dv, s);
            unsigned short h = f2bf_rne(vv[q]);
            float lo = vv[q] - bf2f(h);
            hp[4 * j + q] = h;
            lp[4 * j + q] = f2bf_rne(lo);
        }
    }
    csqf[cell] = (float)s;

    double m = 0.0;
    for (int i = cell; i < NTOK; i += 4096) m += (double)mask[i];
    red[tid] = m;
    __syncthreads();
    for (int st = 128; st > 0; st >>= 1) {
        if (tid < st) red[tid] += red[tid + st];
        __syncthreads();
    }
    if (tid == 0) atomicAdd(mask_sum, red[0]);
}

// ---------------------------------------------------------------------------
// MFMA fast pass. One wave = 16 tokens x 1 codebook over all 512 codes.
// dot = xh*ch + xh*cl + xl*ch accumulated in one MFMA chain (error <= ~2e-6).
// Fragment layouts (m89/m91/m120-verified):
//   A[m = lane&15][k = (lane>>4)*8 + j]   (8 bf16, contiguous dims of token m)
//   B[k = (lane>>4)*8 + j][n = lane&15]   (8 bf16, contiguous dims of code n)
//   C  row = (lane>>4)*4 + reg, col = lane&15
__global__ __launch_bounds__(256) void vq_fast(
    const float* __restrict__ latents, const float* __restrict__ mask,
    const float* __restrict__ cbs, const float* __restrict__ csqf,
    const unsigned short* __restrict__ cbh, const unsigned short* __restrict__ cbl,
    float* __restrict__ out, double* __restrict__ mse_sum,
    float* __restrict__ hist, unsigned* __restrict__ count,
    unsigned* __restrict__ list)
{
    __shared__ int bidflag[4 * 16];

    const int c = blockIdx.x & 7;
    const int grp = blockIdx.x >> 3;              // 1024 groups of 64 tokens
    const int wv = threadIdx.x >> 6;
    const int lane = threadIdx.x & 63;
    const int n = lane & 15;
    const int quad = lane >> 4;
    const int token0 = grp * 64 + wv * 16;

    // A fragment: token token0+n, dims quad*8..+8 of codebook-c slice
    const float* xp = latents + (size_t)(token0 + n) * DD + c * SD + quad * 8;
    bf16x8 ah, al;
    {
        float4 xa = ((const float4*)xp)[0];
        float4 xb = ((const float4*)xp)[1];
        float xv[8] = {xa.x, xa.y, xa.z, xa.w, xb.x, xb.y, xb.z, xb.w};
        #pragma unroll
        for (int j = 0; j < 8; ++j) {
            unsigned short h = f2bf_rne(xv[j]);
            float lo = xv[j] - bf2f(h);
            ah[j] = (short)h;
            al[j] = (short)f2bf_rne(lo);
        }
    }

    const unsigned short* bh_ptr = cbh + ((size_t)(c * KK + n)) * SD + quad * 8;
    const unsigned short* bl_ptr = cbl + ((size_t)(c * KK + n)) * SD + quad * 8;
    const float* csq_ptr = csqf + c * KK + n;

    float best[4] = {1e30f, 1e30f, 1e30f, 1e30f};
    float sec[4]  = {1e30f, 1e30f, 1e30f, 1e30f};
    int   bid[4]  = {0, 0, 0, 0};

    #pragma unroll 2
    for (int t = 0; t < 32; ++t) {
        bf16x8 bh = *(const bf16x8*)(bh_ptr + (size_t)t * 16 * SD);
        bf16x8 bl = *(const bf16x8*)(bl_ptr + (size_t)t * 16 * SD);
        float cs = csq_ptr[t * 16];
        f32x4 acc = {0.f, 0.f, 0.f, 0.f};
        acc = __builtin_amdgcn_mfma_f32_16x16x32_bf16(ah, bh, acc, 0, 0, 0);
        acc = __builtin_amdgcn_mfma_f32_16x16x32_bf16(ah, bl, acc, 0, 0, 0);
        acc = __builtin_amdgcn_mfma_f32_16x16x32_bf16(al, bh, acc, 0, 0, 0);
        const int code = t * 16 + n;
        #pragma unroll
        for (int i = 0; i < 4; ++i) {
            float s = fmaf(-2.f, acc[i], cs);
            bool lt = s < best[i];
            sec[i] = fminf(sec[i], fmaxf(s, best[i]));
            best[i] = fminf(best[i], s);
            bid[i] = lt ? code : bid[i];
        }
    }

    // Reduce (best, sec, bid) across the 16 columns within each quad-group.
    #pragma unroll
    for (int off = 1; off < 16; off <<= 1) {
        #pragma unroll
        for (int i = 0; i < 4; ++i) {
            float ob = __shfl_xor(best[i], off, 64);
            float os = __shfl_xor(sec[i],  off, 64);
            int   od = __shfl_xor(bid[i],  off, 64);
            float hi = fmaxf(best[i], ob);
            sec[i] = fminf(fminf(sec[i], os), hi);
            bool take = (ob < best[i]) || (ob == best[i] && od < bid[i]);
            best[i] = take ? ob : best[i];
            bid[i]  = take ? od : bid[i];
        }
    }

    // Column-0 lane of each quad owns rows quad*4+i
    if (n == 0) {
        #pragma unroll
        for (int i = 0; i < 4; ++i) {
            int r = quad * 4 + i;
            int token = token0 + r;
            out[(size_t)token * CC + c] = (float)bid[i];
            bool flag = (sec[i] - best[i]) < GUARD;
            bidflag[wv * 16 + r] = bid[i] | (flag ? (1 << 20) : 0);
            if (!flag) {
                atomicAdd(&hist[c * KK + bid[i]], mask[token]);
            } else {
                unsigned slot = atomicAdd(count, 1u);
                if (slot < CAP) list[slot] = ((unsigned)token << 3) | (unsigned)c;
            }
        }
    }
    // same-wave LDS RAW: compiler inserts lgkmcnt wait; no barrier needed

    // Epilogue: lane -> (t = lane>>2, part = lane&3): 8 dims of token t
    const int t8 = lane >> 2, part = lane & 3;
    const int etok = token0 + t8;
    const int bf = bidflag[wv * 16 + t8];
    const int ebid = bf & 0xFFFFF;
    const bool eflag = (bf >> 20) & 1;
    const float* qrow = cbs + ((size_t)(c * KK + ebid)) * SD + part * 8;
    const float* xrow = latents + (size_t)etok * DD + c * SD + part * 8;
    float4 q0 = ((const float4*)qrow)[0], q1 = ((const float4*)qrow)[1];
    float4 x0 = ((const float4*)xrow)[0], x1 = ((const float4*)xrow)[1];
    float4 s0, s1;
    s0.x = x0.x + (q0.x - x0.x); s0.y = x0.y + (q0.y - x0.y);
    s0.z = x0.z + (q0.z - x0.z); s0.w = x0.w + (q0.w - x0.w);
    s1.x = x1.x + (q1.x - x1.x); s1.y = x1.y + (q1.y - x1.y);
    s1.z = x1.z + (q1.z - x1.z); s1.w = x1.w + (q1.w - x1.w);
    const size_t obase = (size_t)etok * DD + c * SD + part * 8;
    ((float4*)(out + OFF_Q  + obase))[0] = q0;
    ((float4*)(out + OFF_Q  + obase))[1] = q1;
    ((float4*)(out + OFF_ST + obase))[0] = s0;
    ((float4*)(out + OFF_ST + obase))[1] = s1;

    double dd = 0.0;
    if (!eflag) {
        double d;
        d = (double)x0.x - (double)q0.x; dd = fma(d, d, dd);
        d = (double)x0.y - (double)q0.y; dd = fma(d, d, dd);
        d = (double)x0.z - (double)q0.z; dd = fma(d, d, dd);
        d = (double)x0.w - (double)q0.w; dd = fma(d, d, dd);
        d = (double)x1.x - (double)q1.x; dd = fma(d, d, dd);
        d = (double)x1.y - (double)q1.y; dd = fma(d, d, dd);
        d = (double)x1.z - (double)q1.z; dd = fma(d, d, dd);
        d = (double)x1.w - (double)q1.w; dd = fma(d, d, dd);
    }
    #pragma unroll
    for (int off = 32; off > 0; off >>= 1) dd += __shfl_down(dd, off, 64);
    if (lane == 0) atomicAdd(mse_sum, dd);
}

// ---------------------------------------------------------------------------
// Exact re-resolve (unchanged from round 3, verified absmax 0): bit-for-bit
// np arithmetic for flagged pairs; patches outputs, adds deferred hist/mse.
__global__ __launch_bounds__(256) void vq_resolve(
    const float* __restrict__ latents, const float* __restrict__ mask,
    const float* __restrict__ cbs, const float* __restrict__ csq_g,
    float* __restrict__ out, double* __restrict__ mse_sum,
    float* __restrict__ hist, const unsigned* __restrict__ count,
    const unsigned* __restrict__ list)
{
    unsigned nf = *count; if (nf > CAP) nf = CAP;
    const int lane  = threadIdx.x & 63;
    const int wave  = (blockIdx.x << 2) | (threadIdx.x >> 6);
    const int nwav  = gridDim.x << 2;

    for (unsigned i = wave; i < nf; i += nwav) {
        const unsigned e = list[i];
        const int token = (int)(e >> 3), c = (int)(e & 7u);
        const float* xp = latents + (size_t)token * DD + c * SD;

        double xd[SD]; double xs = 0.0;
        #pragma unroll
        for (int j = 0; j < 8; ++j) {
            float4 v = ((const float4*)xp)[j];
            xd[4*j+0] = (double)v.x; xd[4*j+1] = (double)v.y;
            xd[4*j+2] = (double)v.z; xd[4*j+3] = (double)v.w;
            xs = fma((double)v.x, (double)v.x, xs);
            xs = fma((double)v.y, (double)v.y, xs);
            xs = fma((double)v.z, (double)v.z, xs);
            xs = fma((double)v.w, (double)v.w, xs);
        }
        const float xsqf = (float)xs;
        const float* cbase = cbs + (size_t)c * KK * SD;
        const float* csqc  = csq_g + c * KK;

        float best = 1e30f; int bk = lane * 8;
        for (int j = 0; j < 8; ++j) {
            const int k = lane * 8 + j;
            const float* cw = cbase + k * SD;
            double d0 = 0.0, d1 = 0.0, d2 = 0.0, d3 = 0.0;
            #pragma unroll
            for (int q = 0; q < 8; ++q) {
                d0 = fma((double)cw[4*q+0], xd[4*q+0], d0);
                d1 = fma((double)cw[4*q+1], xd[4*q+1], d1);
                d2 = fma((double)cw[4*q+2], xd[4*q+2], d2);
                d3 = fma((double)cw[4*q+3], xd[4*q+3], d3);
            }
            const float dotf = (float)((d0 + d1) + (d2 + d3));
            const float t1 = xsqf + csqc[k];
            const float dist = t1 - 2.0f * dotf;
            if (dist < best) { best = dist; bk = k; }
        }
        #pragma unroll
        for (int off = 32; off > 0; off >>= 1) {
            float od = __shfl_down(best, off, 64);
            int   ok = __shfl_down(bk,   off, 64);
            if (od < best || (od == best && ok < bk)) { best = od; bk = ok; }
        }
        bk = __shfl(bk, 0, 64);

        const int oldid = (int)out[(size_t)token * CC + c];
        if (bk != oldid) {
            if (lane == 0) out[(size_t)token * CC + c] = (float)bk;
            if (lane < SD) {
                float q = cbase[bk * SD + lane];
                float x = xp[lane];
                out[OFF_Q  + (size_t)token * DD + c * SD + lane] = q;
                out[OFF_ST + (size_t)token * DD + c * SD + lane] = x + (q - x);
            }
        }
        double dd = 0.0;
        if (lane < SD) {
            double q = (double)cbase[bk * SD + lane];
            double df = (double)xp[lane] - q;
            dd = df * df;
        }
        #pragma unroll
        for (int off = 32; off > 0; off >>= 1) dd += __shfl_down(dd, off, 64);
        if (lane == 0) {
            atomicAdd(mse_sum, dd);
            atomicAdd(&hist[c * KK + bk], mask[token]);
        }
    }
}

// ---------------------------------------------------------------------------
__global__ __launch_bounds__(512) void vq_final(
    const float* __restrict__ hist, const double* __restrict__ mse_sum,
    const double* __restrict__ mask_sum, float* __restrict__ out)
{
    __shared__ double ent[CC];
    const int tid = threadIdx.x;
    double denom = *mask_sum; if (denom < 1.0) denom = 1.0;

    const int w = tid >> 6;
    const int lane = tid & 63;
    double t = 0.0;
    for (int k = lane; k < KK; k += 64) {
        double p = (double)hist[w * KK + k] / denom;
        t += p * log(p + 1e-8);
    }
    #pragma unroll
    for (int off = 32; off > 0; off >>= 1) t += __shfl_down(t, off, 64);
    if (lane == 0) ent[w] = -t;
    __syncthreads();

    if (tid == 0) {
        double mean = mse_sum[0] / (double)QN;
        out[OFF_SC + 0] = (float)(0.25 * mean);
        out[OFF_SC + 1] = (float)(1.0 * mean);
        double perp = 0.0;
        for (int cc = 0; cc < CC; ++cc) perp += exp(ent[cc]);
        out[OFF_SC + 2] = (float)(perp / (double)CC);
    }
}

extern "C" void kernel_launch(void* const* d_in, const int* in_sizes, int n_in,
                              void* d_out, int out_size, void* d_ws, size_t ws_size,
                              hipStream_t stream) {
    const float* latents = (const float*)d_in[0];
    const float* mask    = (const float*)d_in[1];
    const float* cbs     = (const float*)d_in[2];
    float* out = (float*)d_out;

    double*         mse      = (double*)((char*)d_ws + WSO_MSE);
    double*         mask_sum = (double*)((char*)d_ws + WSO_MASK);
    unsigned*       count    = (unsigned*)((char*)d_ws + WSO_CNT);
    float*          hist     = (float*)((char*)d_ws + WSO_HIST);
    float*          csqf     = (float*)((char*)d_ws + WSO_CSQ);
    unsigned*       list     = (unsigned*)((char*)d_ws + WSO_LIST);
    unsigned short* cbh      = (unsigned short*)((char*)d_ws + WSO_CBH);
    unsigned short* cbl      = (unsigned short*)((char*)d_ws + WSO_CBL);

    hipMemsetAsync(d_ws, 0, WS_ZERO, stream);

    vq_prep<<<dim3(16), dim3(256), 0, stream>>>(cbs, mask, csqf, cbh, cbl, mask_sum);
    vq_fast<<<dim3((NTOK / 64) * CC), dim3(256), 0, stream>>>(
        latents, mask, cbs, csqf, cbh, cbl, out, mse, hist, count, list);
    vq_resolve<<<dim3(512), dim3(256), 0, stream>>>(
        latents, mask, cbs, csqf, out, mse, hist, count, list);
    vq_final<<<dim3(1), dim3(512), 0, stream>>>(hist, mse, mask_sum, out);
}